// Round 13
// baseline (536.971 us; speedup 1.0000x reference)
//
#include <hip/hip_runtime.h>

// ---------------------------------------------------------------------------
// GCN forward, reassociated: per layer h = relu( (A_hat h) W + b ).
// Structure: bf16 features (pull is L3-restream bound: FETCH = 8 XCDs x |H|),
// binned no-atomic-hotpath CSR build, pull-side aggregation, MFMA GEMM with
// LDS-staged operands, head-dot fused into layer 4, atomic-free pooling.
// R13: pull's inner loop de-chained — edata[j] = (src, bits(dinv[src]))
// precomputed once (edata_fill, after fill_csr completes dinv), so pull
// issues 8 sequential int2 + 8 H-row gathers per batch (was 24 VMEM with a
// dependent random dinv gather in the middle).
// NOTE: harness delivers integer inputs as int32 (edge_index/batch: int*).
// ---------------------------------------------------------------------------

constexpr int D = 128;
constexpr int NGRAPH = 512;
constexpr int CHUNK = 4096;       // edges per scatter block
constexpr int BSH = 9;            // 512 nodes per bucket
constexpr int OP = 136;           // gemm out-tile pitch (ushorts): 272B, 16B-aligned rows

typedef __attribute__((ext_vector_type(8))) short bf16x8;
typedef __attribute__((ext_vector_type(4))) float f32x4;

__device__ __forceinline__ float bf2f(unsigned short b) {
    return __uint_as_float(((unsigned int)b) << 16);
}
__device__ __forceinline__ unsigned short f2bf(float f) {   // round-to-nearest-even
    unsigned int u = __float_as_uint(f);
    u += 0x7FFFu + ((u >> 16) & 1u);
    return (unsigned short)(u >> 16);
}

// merged independent setup: [0,CB) cast x->bf16 | [CB,CB+256) cast W ->
// transposed bf16 Wt | [CB+256, ...) per-chunk bucket histogram.
__global__ __launch_bounds__(256) void setup_all(
        const float4* __restrict__ x4, ushort4* __restrict__ hb, int n4, int CB,
        const float* __restrict__ W, unsigned short* __restrict__ Wt,
        const int* __restrict__ ec, int E, int* __restrict__ bucketCnt) {
    __shared__ int h[256];
    const int t = threadIdx.x;
    const int b = blockIdx.x;
    if (b < CB) {
        int i = b * 256 + t;
        if (i < n4) {
            float4 v = x4[i];
            ushort4 o;
            o.x = f2bf(v.x); o.y = f2bf(v.y); o.z = f2bf(v.z); o.w = f2bf(v.w);
            hb[i] = o;
        }
    } else if (b < CB + 256) {
        int idx = (b - CB) * 256 + t;      // 4*128*128 = 65536 elems
        int i = idx >> 14;
        int rem = idx & 16383;
        int k = rem >> 7, c = rem & 127;
        Wt[(i << 14) + c * 128 + k] = f2bf(W[idx]);
    } else {
        h[t] = 0;
        __syncthreads();
        const int e0 = (b - CB - 256) * CHUNK;
        const int cnt = min(CHUNK, E - e0);
        for (int i = t; i < cnt; i += 256) atomicAdd(&h[ec[e0 + i] >> BSH], 1);
        __syncthreads();
        if (h[t]) atomicAdd(&bucketCnt[t], h[t]);
    }
}

// exclusive scan over 256 bucket counts -> bucketBase, globCursor
__global__ __launch_bounds__(256) void bucket_scan(const int* __restrict__ bucketCnt,
                                                   int* __restrict__ bucketBase,
                                                   int* __restrict__ globCursor) {
    __shared__ int s[256];
    const int t = threadIdx.x;
    int v = bucketCnt[t];
    s[t] = v; __syncthreads();
    for (int off = 1; off < 256; off <<= 1) {
        int x = (t >= off) ? s[t - off] : 0;
        __syncthreads();
        s[t] += x;
        __syncthreads();
    }
    int excl = s[t] - v;
    bucketBase[t] = excl;
    globCursor[t] = excl;
}

// scatter (r,c) pairs into bucket-grouped array, LDS-staged & coalesced
__global__ __launch_bounds__(256) void scatter_pairs(const int* __restrict__ er,
                                                     const int* __restrict__ ec, int E,
                                                     int* __restrict__ globCursor,
                                                     int2* __restrict__ pairs) {
    __shared__ int h[256], lbase[256], cur[256], segd[256], s[256];
    __shared__ int2 stage[CHUNK];
    const int t = threadIdx.x;
    const int e0 = blockIdx.x * CHUNK;
    const int cnt = min(CHUNK, E - e0);

    h[t] = 0;
    __syncthreads();
    for (int i = t; i < cnt; i += 256) atomicAdd(&h[ec[e0 + i] >> BSH], 1);
    __syncthreads();
    int v = h[t];
    s[t] = v; __syncthreads();
    for (int off = 1; off < 256; off <<= 1) {
        int x = (t >= off) ? s[t - off] : 0;
        __syncthreads();
        s[t] += x;
        __syncthreads();
    }
    lbase[t] = s[t] - v;
    cur[t] = s[t] - v;
    segd[t] = atomicAdd(&globCursor[t], v) - lbase[t];
    __syncthreads();
    for (int i = t; i < cnt; i += 256) {
        int c = ec[e0 + i];
        int b = c >> BSH;
        int p = atomicAdd(&cur[b], 1);
        stage[p] = make_int2(er[e0 + i], c);
    }
    __syncthreads();
    for (int i = t; i < cnt; i += 256) {
        int2 pr = stage[i];
        int b = pr.y >> BSH;
        pairs[segd[b] + i] = pr;
    }
}

// one block per bucket. LDS hist+scan -> rowptr, dinv, slot fill.
__global__ __launch_bounds__(256) void fill_csr(const int2* __restrict__ pairs,
                                                const int* __restrict__ bucketBase,
                                                const int* __restrict__ bucketCnt,
                                                int N, int E, int NBUCK,
                                                int* __restrict__ rowptr,
                                                float* __restrict__ dinv,
                                                int* __restrict__ srcs) {
    __shared__ int hist[512], lofs[512], s[256];
    const int t = threadIdx.x;
    const int b = blockIdx.x;
    const int c0 = b << BSH;
    const int base = bucketBase[b];
    const int cnt = bucketCnt[b];
    const int2* pp = pairs + base;

    hist[t] = 0; hist[t + 256] = 0;
    __syncthreads();
    for (int i = t; i < cnt; i += 256) atomicAdd(&hist[pp[i].y - c0], 1);
    __syncthreads();
    int a0 = hist[2 * t], a1 = hist[2 * t + 1];
    s[t] = a0 + a1; __syncthreads();
    for (int off = 1; off < 256; off <<= 1) {
        int x = (t >= off) ? s[t - off] : 0;
        __syncthreads();
        s[t] += x;
        __syncthreads();
    }
    int excl = s[t] - (a0 + a1);
    lofs[2 * t] = excl;
    lofs[2 * t + 1] = excl + a0;
    __syncthreads();
    const int nn = min(512, N - c0);
    for (int i = t; i < nn; i += 256) {
        rowptr[c0 + i] = base + lofs[i];
        dinv[c0 + i] = rsqrtf((float)hist[i] + 1.0f);
    }
    if (b == NBUCK - 1 && t == 0) rowptr[N] = E;
    __syncthreads();
    for (int i = t; i < cnt; i += 256) {
        int2 pr = pp[i];
        int p = atomicAdd(&lofs[pr.y - c0], 1);
        srcs[base + p] = pr.x;
    }
}

// edata[j] = (src, bits(dinv[src])) — runs after fill_csr (dinv complete).
// Sequential read srcs, random dinv gather (L2-resident 400KB), seq write.
__global__ __launch_bounds__(256) void edata_fill(const int* __restrict__ srcs,
                                                  const float* __restrict__ dinv,
                                                  int2* __restrict__ edata, int E) {
    int j = blockIdx.x * 256 + threadIdx.x;
    if (j < E) {
        int r = srcs[j];
        edata[j] = make_int2(r, __float_as_int(dinv[r]));
    }
}

// Pb[n][:] = bf16( dinv[n]*( sum_j s_j*H[r_j][:] + dinv[n]*H[n][:] ) )
// edata stream: (r_j, bits(s_j)) — 8 sequential int2 + 8 H gathers per batch.
__global__ __launch_bounds__(256) void pull_agg(const int* __restrict__ rowptr,
                                                const int2* __restrict__ edata,
                                                const float* __restrict__ dinv,
                                                const unsigned short* __restrict__ H,
                                                unsigned short* __restrict__ Pb, int N) {
    int node = blockIdx.x * 8 + (threadIdx.x >> 5);
    int lane = threadIdx.x & 31;
    if (node >= N) return;
    int j = rowptr[node], end = rowptr[node + 1];
    const ushort4* H2 = (const ushort4*)H;   // 32 ushort4 per row
    float sn = dinv[node];
    ushort4 hs = H2[(size_t)node * 32 + lane];
    float4 acc = make_float4(sn * bf2f(hs.x), sn * bf2f(hs.y),
                             sn * bf2f(hs.z), sn * bf2f(hs.w));
    for (; j + 8 <= end; j += 8) {
        int2 ed[8]; ushort4 h[8];
#pragma unroll
        for (int t = 0; t < 8; ++t) ed[t] = edata[j + t];
#pragma unroll
        for (int t = 0; t < 8; ++t) h[t] = H2[(size_t)ed[t].x * 32 + lane];
#pragma unroll
        for (int t = 0; t < 8; ++t) {
            const float s = __int_as_float(ed[t].y);
            acc.x += s * bf2f(h[t].x); acc.y += s * bf2f(h[t].y);
            acc.z += s * bf2f(h[t].z); acc.w += s * bf2f(h[t].w);
        }
    }
    for (; j < end; ++j) {
        int2 ed = edata[j];
        const float s = __int_as_float(ed.y);
        ushort4 h0 = H2[(size_t)ed.x * 32 + lane];
        acc.x += s * bf2f(h0.x); acc.y += s * bf2f(h0.y);
        acc.z += s * bf2f(h0.z); acc.w += s * bf2f(h0.w);
    }
    ushort4 o;
    o.x = f2bf(sn * acc.x); o.y = f2bf(sn * acc.y);
    o.z = f2bf(sn * acc.z); o.w = f2bf(sn * acc.w);
    ((ushort4*)Pb)[(size_t)node * 32 + lane] = o;
}

// Hn = bf16( relu( Pb @ W + bias ) ) via 16x16x32 bf16 MFMA.
// Block = 4 waves; wave = 32 rows (2 row-tiles, W-frag reuse x2).
// A staged via coalesced loads into xor-swizzled LDS; LDS reused as bf16 out
// tile for coalesced stores. Layer 4 (writeDots): head dot fused, no Hn write.
// C/D: col=lane&15, row=(lane>>4)*4+reg (verified mapping).
__global__ __launch_bounds__(256) void gemm_mfma(const unsigned short* __restrict__ Pb,
                                                 const unsigned short* __restrict__ Wt,
                                                 const float* __restrict__ bias,
                                                 unsigned short* __restrict__ Hn,
                                                 float* __restrict__ dots,
                                                 const float* __restrict__ Wl,
                                                 int writeDots) {
    __shared__ __align__(16) unsigned short u[4][32 * OP];   // 34 KB
    const int wave = threadIdx.x >> 6;
    const int lane = threadIdx.x & 63;
    const int row16 = lane & 15;
    const int quad = lane >> 4;
    const int r0 = blockIdx.x * 128 + wave * 32;
    unsigned short* U = u[wave];

    // ---- stage 32 rows (A-layout: pitch 128, xor-swizzled 16B chunks) ----
    {
        const int lr = lane >> 1, hf = lane & 1;   // lane covers 128B of row lr
        const bf16x8* g = (const bf16x8*)(Pb + (size_t)(r0 + lr) * 128);
        bf16x8* l = (bf16x8*)(U + lr * 128);
#pragma unroll
        for (int i = 0; i < 8; ++i) {
            int c = hf * 8 + i;
            l[c ^ (lr & 15)] = g[c];
        }
    }
    __syncthreads();

    // ---- A fragments for both 16-row tiles, all 4 K-chunks ----
    bf16x8 a0[4], a1[4];
#pragma unroll
    for (int kc = 0; kc < 4; ++kc) {
        const int ph = (kc * 4 + quad) ^ row16;
        a0[kc] = *(const bf16x8*)(U + row16 * 128 + ph * 8);
        a1[kc] = *(const bf16x8*)(U + (16 + row16) * 128 + ph * 8);
    }
    __syncthreads();   // U is now reused as the out tile (pitch OP)

    float rd0[4] = {0.f, 0.f, 0.f, 0.f}, rd1[4] = {0.f, 0.f, 0.f, 0.f};
#pragma unroll
    for (int ct = 0; ct < 8; ++ct) {
        const int col = ct * 16 + row16;
        const bf16x8* wc = (const bf16x8*)(Wt + (size_t)col * 128);
        f32x4 acc0 = {0.f, 0.f, 0.f, 0.f}, acc1 = {0.f, 0.f, 0.f, 0.f};
#pragma unroll
        for (int kc = 0; kc < 4; ++kc) {
            const bf16x8 wf = wc[kc * 4 + quad];
            acc0 = __builtin_amdgcn_mfma_f32_16x16x32_bf16(a0[kc], wf, acc0, 0, 0, 0);
            acc1 = __builtin_amdgcn_mfma_f32_16x16x32_bf16(a1[kc], wf, acc1, 0, 0, 0);
        }
        const float bv = bias[col];
        if (writeDots) {
            const float wl = Wl[col];
#pragma unroll
            for (int i = 0; i < 4; ++i) {
                rd0[i] += fmaxf(acc0[i] + bv, 0.f) * wl;
                rd1[i] += fmaxf(acc1[i] + bv, 0.f) * wl;
            }
        } else {
#pragma unroll
            for (int i = 0; i < 4; ++i) {
                U[(quad * 4 + i) * OP + col] = f2bf(fmaxf(acc0[i] + bv, 0.f));
                U[(16 + quad * 4 + i) * OP + col] = f2bf(fmaxf(acc1[i] + bv, 0.f));
            }
        }
    }

    if (writeDots) {
#pragma unroll
        for (int m = 1; m < 16; m <<= 1)
#pragma unroll
            for (int i = 0; i < 4; ++i) {
                rd0[i] += __shfl_xor(rd0[i], m, 64);
                rd1[i] += __shfl_xor(rd1[i], m, 64);
            }
        if (row16 == 0) {
#pragma unroll
            for (int i = 0; i < 4; ++i) {
                dots[r0 + quad * 4 + i] = rd0[i];
                dots[r0 + 16 + quad * 4 + i] = rd1[i];
            }
        }
    } else {
        __syncthreads();
        // coalesced readback + store: 512 16B chunks per wave tile, 8/lane
#pragma unroll
        for (int i = 0; i < 8; ++i) {
            int idx = i * 64 + lane;
            int row = idx >> 4, c8 = idx & 15;
            bf16x8 v = *(const bf16x8*)(U + row * OP + c8 * 8);
            *(bf16x8*)(Hn + (size_t)(r0 + row) * 128 + c8 * 8) = v;
        }
    }
}

// one block per graph: binary-search node range in sorted batch, mean, +bl
__global__ __launch_bounds__(256) void pool_graphs(const float* __restrict__ dots,
                                                   const int* __restrict__ batch, int N,
                                                   const float* __restrict__ bl,
                                                   float* __restrict__ out) {
    __shared__ int bounds[2];
    __shared__ float red[4];
    const int g = blockIdx.x;
    const int t = threadIdx.x;
    if (t < 2) {
        int key = g + t;             // lower_bound(batch, key)
        int lo = 0, hi = N;
        while (lo < hi) {
            int mid = (lo + hi) >> 1;
            if (batch[mid] < key) lo = mid + 1; else hi = mid;
        }
        bounds[t] = lo;
    }
    __syncthreads();
    const int lo = bounds[0], hi = bounds[1];
    float s = 0.f;
    for (int i = lo + t; i < hi; i += 256) s += dots[i];
#pragma unroll
    for (int off = 32; off > 0; off >>= 1) s += __shfl_down(s, off, 64);
    if ((t & 63) == 0) red[t >> 6] = s;
    __syncthreads();
    if (t == 0) {
        float tot = red[0] + red[1] + red[2] + red[3];
        int cnt = hi - lo;
        out[g] = tot / (float)(cnt > 0 ? cnt : 1) + bl[0];
    }
}

extern "C" void kernel_launch(void* const* d_in, const int* in_sizes, int n_in,
                              void* d_out, int out_size, void* d_ws, size_t ws_size,
                              hipStream_t stream) {
    const float* x     = (const float*)d_in[0];
    const int*   eidx  = (const int*)d_in[1];    // int32 (harness converts int64)
    const int*   batch = (const int*)d_in[2];
    const float* Ws    = (const float*)d_in[3];
    const float* bs    = (const float*)d_in[4];
    const float* Wl    = (const float*)d_in[5];
    const float* bl    = (const float*)d_in[6];
    (void)n_in; (void)out_size;

    const int N = in_sizes[0] / D;
    const int E = in_sizes[1] / 2;
    const int* er = eidx;       // sources
    const int* ec = eidx + E;   // targets
    const int NBUCK = (N + 511) >> BSH;          // 512-node buckets (<= 256)
    const int NCHUNK = (E + CHUNK - 1) / CHUNK;

    // ---- workspace carve ----
    const int Npad = (N + 127) & ~127;           // gemm processes 128 rows/block
    const size_t hBytes = (size_t)Npad * D * sizeof(unsigned short); // 25.6 MB bf16
    auto al = [](size_t v) { return (v + 255) & ~(size_t)255; };
    char* base = (char*)d_ws;
    size_t off = 0;

    unsigned short* Pb = (unsigned short*)base;  off = al(hBytes);
    int2* pairs = (int2*)Pb;                     // aliases Pb (CSR build precedes layers)
    int* bucketCnt  = (int*)(base + off);
    int* globCursor = bucketCnt + 256;
    off = al(off + 512 * sizeof(int));
    int*   bucketBase = (int*)(base + off);  off = al(off + 256 * sizeof(int));
    float* dinv   = (float*)(base + off);    off = al(off + (size_t)Npad * sizeof(float));
    float* dots   = (float*)(base + off);    off = al(off + (size_t)Npad * sizeof(float));
    int*   rowptr = (int*)(base + off);      off = al(off + (size_t)(Npad + 64) * sizeof(int));
    int*   srcs   = (int*)(base + off);      off = al(off + (size_t)E * sizeof(int));
    int2*  edata  = (int2*)(base + off);     off = al(off + (size_t)E * sizeof(int2));
    unsigned short* Wt = (unsigned short*)(base + off);   off = al(off + 4 * 128 * 128 * sizeof(unsigned short));
    unsigned short* Hb0 = (unsigned short*)(base + off);  off = al(off + hBytes);

    // second bf16 buffer: in ws if it fits, else reuse x's 51.2 MB input buffer
    // (Npad*256B <= N*512B, so the alias stays in-bounds)
    const bool twoBuf = ws_size >= off + hBytes;
    unsigned short* Hb1 = twoBuf ? (unsigned short*)(base + off)
                                 : (unsigned short*)d_in[0];
    unsigned short* hb[2] = { Hb0, Hb1 };

    // ---- setup: memset bucketCnt; merged cast_x | cast_W | histogram ----
    hipMemsetAsync(bucketCnt, 0, 256 * sizeof(int), stream);
    const int n4 = N * D / 4;
    const int CB = (n4 + 255) / 256;
    setup_all<<<CB + 256 + NCHUNK, 256, 0, stream>>>((const float4*)x, (ushort4*)Hb0,
                                                     n4, CB, Ws, Wt, ec, E, bucketCnt);

    // ---- binned CSR build (once; reused by all 4 layers) ----
    bucket_scan<<<1, 256, 0, stream>>>(bucketCnt, bucketBase, globCursor);
    scatter_pairs<<<NCHUNK, 256, 0, stream>>>(er, ec, E, globCursor, pairs);
    fill_csr<<<NBUCK, 256, 0, stream>>>(pairs, bucketBase, bucketCnt, N, E, NBUCK,
                                        rowptr, dinv, srcs);
    edata_fill<<<(E + 255) / 256, 256, 0, stream>>>(srcs, dinv, edata, E);

    // ---- 4 layers: pull (bf16 gather -> bf16 Pb) -> MFMA gemm ----
    for (int i = 0; i < 4; ++i) {
        const unsigned short* Hc = hb[i & 1];
        unsigned short* Hn = hb[(i + 1) & 1];
        pull_agg<<<(N + 7) / 8, 256, 0, stream>>>(rowptr, edata, dinv, Hc, Pb, N);
        gemm_mfma<<<Npad / 128, 256, 0, stream>>>(Pb, Wt + (size_t)i * D * D,
                                                  bs + (size_t)i * D, Hn, dots, Wl,
                                                  (i == 3) ? 1 : 0);
    }

    // ---- mean pool (+bl) over fused per-node dots ----
    pool_graphs<<<NGRAPH, 256, 0, stream>>>(dots, batch, N, bl, (float*)d_out);
}